// Round 9
// baseline (37.003 us; speedup 1.0000x reference)
//
#include <hip/hip_runtime.h>

#define EPS 1e-7f
#define NB 64
#define NI 1152
#define NJ 8
#define NK 43
#define NL 16
#define KL (NK*NL)        // 688
#define THREADS 704       // 11 waves
#define CHUNK 576
#define NCHUNK 2          // NI / CHUNK
#define NKG 11            // groups of 4 k's (44 = NK+1 pad)
#define CPS 580           // float4 row stride for cP (576 + 4 pad)
#define SVP 20            // sV row stride (floats; 80B -> float4-aligned rows)
#define WVSZ 352          // NJ*44

// fused squash: s-values for one k-row live in a 16-lane group (t = tid, t<688)
__device__ __forceinline__ float squash_scale(float sv) {
    float sq = sv * sv;
    sq += __shfl_xor(sq, 1);
    sq += __shfl_xor(sq, 2);
    sq += __shfl_xor(sq, 4);
    sq += __shfl_xor(sq, 8);
    const float scale = sq / ((1.f + sq) * sqrtf(sq + EPS));
    return scale * sv;
}

__global__ __launch_bounds__(THREADS, 3)
void caps_fused(const float* __restrict__ X, const float* __restrict__ W,
                float* __restrict__ out) {
    __shared__ __align__(16) float4 sXa[NI];        // x[i][0:4]   18,432 B
    __shared__ __align__(16) float4 sXb[NI];        // x[i][4:8]   18,432 B
    __shared__ __align__(16) float4 cP[NKG*CPS];    // packed c   102,080 B
    __shared__ __align__(16) float sWv[NJ*44];      // Wv accum     1,408 B
    __shared__ __align__(16) float sV[NK*SVP];      //              3,440 B
    __shared__ __align__(16) float sG[WVSZ];        //              1,408 B
    __shared__ __align__(16) float4 xsW[2*NKG];     // xs partials    352 B
    __shared__ float sXs[NJ];

    const int tid = threadIdx.x;
    const int b = blockIdx.x;
    const float* Xb = X + (size_t)b * (NI*NJ);
    const float4* X4 = (const float4*)Xb;

    // ---- load X into LDS planes + xs partial sums (single global pass) ----
    {
        float4 ax = make_float4(0.f, 0.f, 0.f, 0.f);
        for (int t = tid; t < NI*2; t += THREADS) {   // THREADS even -> parity(t)==parity(tid)
            float4 v = X4[t];
            if (t & 1) sXb[t >> 1] = v; else sXa[t >> 1] = v;
            ax.x += v.x; ax.y += v.y; ax.z += v.z; ax.w += v.w;
        }
        #pragma unroll
        for (int m = 2; m <= 32; m <<= 1) {           // reduce per parity class
            ax.x += __shfl_xor(ax.x, m);
            ax.y += __shfl_xor(ax.y, m);
            ax.z += __shfl_xor(ax.z, m);
            ax.w += __shfl_xor(ax.w, m);
        }
        if ((tid & 63) < 2) xsW[(tid >> 6)*2 + (tid & 1)] = ax;
    }
    __syncthreads();
    if (tid < NJ) {
        const float* f = (const float*)xsW;
        float s = 0.f;
        #pragma unroll
        for (int w = 0; w < 11; ++w) s += f[(w*2 + (tid >> 2))*4 + (tid & 3)];
        sXs[tid] = s;
    }
    __syncthreads();
    // ---- fused s0 -> squash -> v0 ----
    if (tid < KL) {
        float sv = 0.f;
        #pragma unroll
        for (int j = 0; j < NJ; ++j) sv = fmaf(sXs[j], W[j*KL + tid], sv);
        sv *= (1.0f/43.0f);
        sV[(tid >> 4)*SVP + (tid & 15)] = squash_scale(sv);
    }
    __syncthreads();
    // ---- Wv0[j,k] ----
    if (tid < WVSZ) {
        const int j = tid / 44, k = tid % 44;
        float wv = 0.f;
        if (k < NK) {
            const float4* Wr = (const float4*)(W + j*KL + k*NL);
            const float4* Vr = (const float4*)&sV[k*SVP];
            #pragma unroll
            for (int q = 0; q < 4; ++q) {
                float4 w4 = Wr[q], v4 = Vr[q];
                wv += w4.x*v4.x + w4.y*v4.y + w4.z*v4.z + w4.w*v4.w;
            }
        }
        sWv[tid] = wv;
    }
    __syncthreads();

    // ---- routing passes ----
    for (int pass = 0; pass < 2; ++pass) {
        float acc[4][8];
        #pragma unroll
        for (int q = 0; q < 4; ++q)
            #pragma unroll
            for (int j = 0; j < 8; ++j) acc[q][j] = 0.f;

        for (int ch = 0; ch < NCHUNK; ++ch) {
            // Phase A: logits + softmax (compute in regs BEFORE barrier)
            float a[44];
            if (tid < CHUNK) {
                const int i = ch*CHUNK + tid;
                float4 x0 = sXa[i], x1 = sXb[i];
                float xr[NJ] = {x0.x, x0.y, x0.z, x0.w, x1.x, x1.y, x1.z, x1.w};
                #pragma unroll
                for (int k = 0; k < 44; ++k) a[k] = 0.f;
                #pragma unroll
                for (int j = 0; j < NJ; ++j) {
                    #pragma unroll
                    for (int k4 = 0; k4 < NKG; ++k4) {
                        float4 wv = *(const float4*)&sWv[j*44 + k4*4];
                        a[k4*4+0] = fmaf(xr[j], wv.x, a[k4*4+0]);
                        a[k4*4+1] = fmaf(xr[j], wv.y, a[k4*4+1]);
                        a[k4*4+2] = fmaf(xr[j], wv.z, a[k4*4+2]);
                        a[k4*4+3] = fmaf(xr[j], wv.w, a[k4*4+3]);
                    }
                }
                float m0=a[0], m1=a[1], m2=a[2], m3=a[3];
                #pragma unroll
                for (int k = 4; k < 40; k += 4) {
                    m0 = fmaxf(m0, a[k+0]); m1 = fmaxf(m1, a[k+1]);
                    m2 = fmaxf(m2, a[k+2]); m3 = fmaxf(m3, a[k+3]);
                }
                m0 = fmaxf(m0, a[40]); m1 = fmaxf(m1, a[41]); m2 = fmaxf(m2, a[42]);
                const float m = fmaxf(fmaxf(m0, m1), fmaxf(m2, m3));
                float z0=0.f, z1=0.f, z2=0.f, z3=0.f;
                #pragma unroll
                for (int k = 0; k < 40; k += 4) {
                    a[k+0] = __expf(a[k+0]-m); z0 += a[k+0];
                    a[k+1] = __expf(a[k+1]-m); z1 += a[k+1];
                    a[k+2] = __expf(a[k+2]-m); z2 += a[k+2];
                    a[k+3] = __expf(a[k+3]-m); z3 += a[k+3];
                }
                a[40] = __expf(a[40]-m); z0 += a[40];
                a[41] = __expf(a[41]-m); z1 += a[41];
                a[42] = __expf(a[42]-m); z2 += a[42];
                const float inv = 1.f / ((z0+z1) + (z2+z3));
                #pragma unroll
                for (int k = 0; k < NK; ++k) a[k] *= inv;
                a[43] = 0.f;
            }
            __syncthreads();   // previous chunk's B done reading cP
            if (tid < CHUNK) {
                #pragma unroll
                for (int kg = 0; kg < NKG; ++kg)
                    cP[kg*CPS + tid] = make_float4(a[4*kg], a[4*kg+1], a[4*kg+2], a[4*kg+3]);
            }
            __syncthreads();   // cP ready
            // Phase B: all 11 waves, kg = wave index, 9 iters
            {
                const int kg = tid >> 6, s = tid & 63;
                #pragma unroll
                for (int ii = 0; ii < CHUNK/64; ++ii) {
                    const int il = s + 64*ii;
                    const int gi = ch*CHUNK + il;
                    float4 c4 = cP[kg*CPS + il];
                    float4 xa = sXa[gi], xb = sXb[gi];
                    acc[0][0]=fmaf(c4.x,xa.x,acc[0][0]); acc[0][1]=fmaf(c4.x,xa.y,acc[0][1]);
                    acc[0][2]=fmaf(c4.x,xa.z,acc[0][2]); acc[0][3]=fmaf(c4.x,xa.w,acc[0][3]);
                    acc[0][4]=fmaf(c4.x,xb.x,acc[0][4]); acc[0][5]=fmaf(c4.x,xb.y,acc[0][5]);
                    acc[0][6]=fmaf(c4.x,xb.z,acc[0][6]); acc[0][7]=fmaf(c4.x,xb.w,acc[0][7]);
                    acc[1][0]=fmaf(c4.y,xa.x,acc[1][0]); acc[1][1]=fmaf(c4.y,xa.y,acc[1][1]);
                    acc[1][2]=fmaf(c4.y,xa.z,acc[1][2]); acc[1][3]=fmaf(c4.y,xa.w,acc[1][3]);
                    acc[1][4]=fmaf(c4.y,xb.x,acc[1][4]); acc[1][5]=fmaf(c4.y,xb.y,acc[1][5]);
                    acc[1][6]=fmaf(c4.y,xb.z,acc[1][6]); acc[1][7]=fmaf(c4.y,xb.w,acc[1][7]);
                    acc[2][0]=fmaf(c4.z,xa.x,acc[2][0]); acc[2][1]=fmaf(c4.z,xa.y,acc[2][1]);
                    acc[2][2]=fmaf(c4.z,xa.z,acc[2][2]); acc[2][3]=fmaf(c4.z,xa.w,acc[2][3]);
                    acc[2][4]=fmaf(c4.z,xb.x,acc[2][4]); acc[2][5]=fmaf(c4.z,xb.y,acc[2][5]);
                    acc[2][6]=fmaf(c4.z,xb.z,acc[2][6]); acc[2][7]=fmaf(c4.z,xb.w,acc[2][7]);
                    acc[3][0]=fmaf(c4.w,xa.x,acc[3][0]); acc[3][1]=fmaf(c4.w,xa.y,acc[3][1]);
                    acc[3][2]=fmaf(c4.w,xa.z,acc[3][2]); acc[3][3]=fmaf(c4.w,xa.w,acc[3][3]);
                    acc[3][4]=fmaf(c4.w,xb.x,acc[3][4]); acc[3][5]=fmaf(c4.w,xb.y,acc[3][5]);
                    acc[3][6]=fmaf(c4.w,xb.z,acc[3][6]); acc[3][7]=fmaf(c4.w,xb.w,acc[3][7]);
                }
            }
        }
        // ---- 64-lane butterfly reduce: value v = bits 5..1 of lane; final
        //      mask-1 combine folds the odd/even lane halves (lane l and l^1
        //      hold the SAME value index) -> full 64-lane sum ----
        {
            float cur[32];
            #pragma unroll
            for (int q = 0; q < 4; ++q)
                #pragma unroll
                for (int j = 0; j < 8; ++j) cur[q*8+j] = acc[q][j];
            #pragma unroll
            for (int lvl = 0; lvl < 5; ++lvl) {
                const int m = 32 >> lvl;           // 32,16,8,4,2
                const bool up = (tid & m) != 0;
                #pragma unroll
                for (int v = 0; v < (32 >> lvl) / 2; ++v) {
                    float give = up ? cur[v] : cur[v + (m >> 1)];
                    float keep = up ? cur[v + (m >> 1)] : cur[v];
                    cur[v] = keep + __shfl_xor(give, m);
                }
            }
            cur[0] += __shfl_xor(cur[0], 1);       // FINAL combine: same value, other parity
            if (!(tid & 1))
                sG[(tid >> 6)*32 + ((tid & 63) >> 1)] = cur[0];  // = G[k*8+j]
        }
        __syncthreads();
        // ---- fused s -> squash -> (sV | out) ----
        if (tid < KL) {
            const int k8 = (tid >> 4)*8;
            float sv = 0.f;
            #pragma unroll
            for (int j = 0; j < NJ; ++j) sv = fmaf(sG[k8 + j], W[j*KL + tid], sv);
            float r = squash_scale(sv);
            if (pass == 1) out[(size_t)b*KL + tid] = r;
            else           sV[(tid >> 4)*SVP + (tid & 15)] = r;
        }
        if (pass == 0) {
            __syncthreads();
            // WvAcc += Wv1
            if (tid < WVSZ) {
                const int j = tid / 44, k = tid % 44;
                float wv = 0.f;
                if (k < NK) {
                    const float4* Wr = (const float4*)(W + j*KL + k*NL);
                    const float4* Vr = (const float4*)&sV[k*SVP];
                    #pragma unroll
                    for (int q = 0; q < 4; ++q) {
                        float4 w4 = Wr[q], v4 = Vr[q];
                        wv += w4.x*v4.x + w4.y*v4.y + w4.z*v4.z + w4.w*v4.w;
                    }
                }
                sWv[tid] += wv;
            }
            __syncthreads();
        }
    }
}

extern "C" void kernel_launch(void* const* d_in, const int* in_sizes, int n_in,
                              void* d_out, int out_size, void* d_ws, size_t ws_size,
                              hipStream_t stream) {
    const float* X = (const float*)d_in[0];   // [64,1152,8]
    const float* W = (const float*)d_in[1];   // [8,43,16]
    float* out = (float*)d_out;               // [64,43,16]
    hipLaunchKernelGGL(caps_fused, dim3(NB), dim3(THREADS), 0, stream, X, W, out);
}